// Round 7
// baseline (911.287 us; speedup 1.0000x reference)
//
#include <hip/hip_runtime.h>

#define NROWS 16384
#define DIMIN 768
#define CD    256
#define KC    4096

#define BM 128
#define BN 128
#define BK 32
#define MARGIN 0.05f
#define NGROUP 256   // 4096 codes / 16 per group

typedef __attribute__((ext_vector_type(8))) short short8;
typedef __attribute__((ext_vector_type(4))) float f32x4;
typedef __attribute__((ext_vector_type(4))) _Float16 f16x4;

#define SWZ(r) ((((r) + ((r) >> 2))) & 3)
#define ASYNC_CP16(gp, lp)                                                     \
    __builtin_amdgcn_global_load_lds(                                          \
        (const __attribute__((address_space(1))) void*)(gp),                   \
        (__attribute__((address_space(3))) void*)(lp), 16, 0, 0)

// ---------------- helpers ----------------
__device__ __forceinline__ float wave_sum(float v) {
#pragma unroll
    for (int off = 32; off > 0; off >>= 1) v += __shfl_xor(v, off, 64);
    return v;
}
__device__ __forceinline__ unsigned short f2bf(float f) {
    unsigned u = __float_as_uint(f);
    unsigned r = (u + 0x7FFFu + ((u >> 16) & 1u)) >> 16;
    return (unsigned short)r;
}

// ---------------- shared MFMA core: acc[i][j] += Arows_tile . Brows_tile^T ----------------
__device__ __forceinline__ void mfma_core(const unsigned short* __restrict__ Arows,
                                          const unsigned short* __restrict__ Brows,
                                          int mBase, int nBase,
                                          unsigned short* As, unsigned short* Bs,
                                          f32x4 acc[4][4], int t) {
    int w = t >> 6, lane = t & 63;
    int wm = (w >> 1) * 64, wn = (w & 1) * 64;
    int g = lane >> 4, c = lane & 15;

    for (int kB = 0; kB < CD; kB += BK) {
        __syncthreads();
#pragma unroll
        for (int it = 0; it < 2; ++it) {
            int L = w * 128 + it * 64 + lane;  // 16B-chunk index in tile
            int r = L >> 2, p = L & 3;
            int q = p ^ SWZ(r);
            ASYNC_CP16(Arows + (size_t)(mBase + r) * CD + kB + q * 8,
                       &As[(w * 128 + it * 64) * 8]);
            ASYNC_CP16(Brows + (size_t)(nBase + r) * CD + kB + q * 8,
                       &Bs[(w * 128 + it * 64) * 8]);
        }
        __syncthreads();
        short8 a[4], b[4];
#pragma unroll
        for (int i = 0; i < 4; ++i) {
            int ra = wm + i * 16 + c;
            a[i] = *(const short8*)&As[ra * 32 + ((g ^ SWZ(ra)) << 3)];
            int rb = wn + i * 16 + c;
            b[i] = *(const short8*)&Bs[rb * 32 + ((g ^ SWZ(rb)) << 3)];
        }
#pragma unroll
        for (int i = 0; i < 4; ++i)
#pragma unroll
            for (int j = 0; j < 4; ++j)
                acc[i][j] = __builtin_amdgcn_mfma_f32_16x16x32_bf16(a[i], b[j], acc[i][j], 0, 0, 0);
    }
}

// ---------------- fused preamble: enc GEMM (blocks 0..1023) ||
//                  E->bf16+e2 (blocks 1024..5119) || W_dec->WdT (blocks 5120..5887) ----------------
__global__ __launch_bounds__(256)
void preamble_kernel(const float* __restrict__ A, const float* __restrict__ B,
                     const float* __restrict__ bias, float* __restrict__ C,
                     const float* __restrict__ E1, const float* __restrict__ E2,
                     const float* __restrict__ E3, const float* __restrict__ E4,
                     unsigned short* __restrict__ Ebf, float* __restrict__ e2,
                     const float* __restrict__ Wd, unsigned short* __restrict__ WdT) {
    int bid = blockIdx.x;
    int t = threadIdx.x;
    if (bid < 1024) {
        // ---- fp32 encoder GEMM, 64x64 tiles (identical to enc_gemm64) ----
        __shared__ float As[BK][64 + 4];
        __shared__ float Bs[BK][64 + 4];
        const int Kt = DIMIN, Nt = CD;
        int mb = bid >> 2, nb = bid & 3;
        int mBase = mb * 64, nBase = nb * 64;
        int mg = t >> 4, ng = t & 15;

        float acc[4][4];
#pragma unroll
        for (int i = 0; i < 4; ++i)
#pragma unroll
            for (int j = 0; j < 4; ++j) acc[i][j] = 0.f;

        for (int kB = 0; kB < Kt; kB += BK) {
#pragma unroll
            for (int i = 0; i < 2; ++i) {  // stage A (transpose)
                int idx = i * 256 + t;
                int row = idx >> 3, k4 = idx & 7;
                float4 g = *(const float4*)(A + (size_t)(mBase + row) * Kt + kB + k4 * 4);
                As[k4 * 4 + 0][row] = g.x;
                As[k4 * 4 + 1][row] = g.y;
                As[k4 * 4 + 2][row] = g.z;
                As[k4 * 4 + 3][row] = g.w;
            }
#pragma unroll
            for (int i = 0; i < 2; ++i) {  // stage B
                int idx = i * 256 + t;
                int row = idx >> 4, c4 = idx & 15;
                float4 g = *(const float4*)(B + (size_t)(kB + row) * Nt + nBase + c4 * 4);
                *(float4*)&Bs[row][c4 * 4] = g;
            }
            __syncthreads();
#pragma unroll 8
            for (int kk = 0; kk < BK; ++kk) {
                float4 a0 = *(const float4*)&As[kk][mg * 4];
                float4 b0 = *(const float4*)&Bs[kk][ng * 4];
                float av[4] = {a0.x, a0.y, a0.z, a0.w};
                float bv[4] = {b0.x, b0.y, b0.z, b0.w};
#pragma unroll
                for (int im = 0; im < 4; ++im)
#pragma unroll
                    for (int in = 0; in < 4; ++in)
                        acc[im][in] = fmaf(av[im], bv[in], acc[im][in]);
            }
            __syncthreads();
        }
        float bv[4];
#pragma unroll
        for (int in = 0; in < 4; ++in) bv[in] = bias[nBase + ng * 4 + in];
#pragma unroll
        for (int im = 0; im < 4; ++im) {
            float4 o = make_float4(acc[im][0] + bv[0], acc[im][1] + bv[1],
                                   acc[im][2] + bv[2], acc[im][3] + bv[3]);
            *(float4*)(C + (size_t)(mBase + mg * 4 + im) * Nt + nBase + ng * 4) = o;
        }
    } else if (bid < 1024 + 4096) {
        // ---- E -> bf16 + e2 (identical to ecvt_kernel) ----
        int vb = bid - 1024;
        int gw   = (vb * 256 + t) >> 6;  // 0..16383
        int lane = t & 63;
        int cb = gw >> 12, r = gw & (KC - 1);
        const float* E = (cb == 0) ? E1 : (cb == 1) ? E2 : (cb == 2) ? E3 : E4;
        float4 v = *(const float4*)(E + (size_t)r * CD + lane * 4);
        float s  = v.x * v.x + v.y * v.y + v.z * v.z + v.w * v.w;
        s = wave_sum(s);
        if (lane == 0) e2[gw] = s;
        ushort4 o = make_ushort4(f2bf(v.x), f2bf(v.y), f2bf(v.z), f2bf(v.w));
        *(ushort4*)(Ebf + (size_t)gw * CD + lane * 4) = o;
    } else {
        // ---- W_dec (256x768) -> WdT (768x256 bf16, transposed) ----
        int vb = bid - (1024 + 4096);
        int gid = vb * 256 + t;  // 0..196607
        int k = gid / DIMIN, n = gid % DIMIN;
        WdT[(size_t)n * CD + k] = f2bf(Wd[gid]);
    }
}

// ---------------- ze1 -> bf16 + z2 ----------------
__global__ void zecvt_kernel(const float* __restrict__ ze, unsigned short* __restrict__ zebf,
                             float* __restrict__ z2) {
    int gw   = (blockIdx.x * blockDim.x + threadIdx.x) >> 6;
    int lane = threadIdx.x & 63;
    float4 v = *(const float4*)(ze + (size_t)gw * CD + lane * 4);
    float s  = v.x * v.x + v.y * v.y + v.z * v.z + v.w * v.w;
    s = wave_sum(s);
    if (lane == 0) z2[gw] = s;
    ushort4 o = make_ushort4(f2bf(v.x), f2bf(v.y), f2bf(v.z), f2bf(v.w));
    *(ushort4*)(zebf + (size_t)gw * CD + lane * 4) = o;
}

// ---------------- VQ pass A: d' = e2 - 2*(ze.E^T) bf16 MFMA, per-16-code-group min (fp16) ----------------
__global__ __launch_bounds__(256)
void vq_minA(const unsigned short* __restrict__ zebf, const unsigned short* __restrict__ Ebf,
             const float* __restrict__ e2s, _Float16* __restrict__ pmin) {
    __shared__ unsigned short As[BM * BK];
    __shared__ unsigned short Bs[BN * BK];
    int mBase = (blockIdx.x >> 5) * BM;
    int nBase = (blockIdx.x & 31) * BN;
    int t = threadIdx.x;
    f32x4 acc[4][4];
    f32x4 zero = {0.f, 0.f, 0.f, 0.f};
#pragma unroll
    for (int i = 0; i < 4; ++i)
#pragma unroll
        for (int j = 0; j < 4; ++j) acc[i][j] = zero;

    mfma_core(zebf, Ebf, mBase, nBase, As, Bs, acc, t);

    int w = t >> 6, lane = t & 63;
    int wm = (w >> 1) * 64, wn = (w & 1) * 64;
    int g = lane >> 4, c = lane & 15;
    float e2v[4];
#pragma unroll
    for (int j = 0; j < 4; ++j) e2v[j] = e2s[nBase + wn + j * 16 + c];
    int gb = (nBase + wn) >> 4;  // first of 4 consecutive 16-code groups this lane covers
#pragma unroll
    for (int i = 0; i < 4; ++i) {
#pragma unroll
        for (int rr = 0; rr < 4; ++rr) {
            float dj[4];
#pragma unroll
            for (int j = 0; j < 4; ++j) dj[j] = fmaf(-2.f, acc[i][j][rr], e2v[j]);
            // min over the 16 lanes (c dim) of each j -> group-of-16 mins
#pragma unroll
            for (int off = 1; off < 16; off <<= 1) {
#pragma unroll
                for (int j = 0; j < 4; ++j)
                    dj[j] = fminf(dj[j], __shfl_xor(dj[j], off, 64));
            }
            if (c == 0) {
                int row = mBase + wm + i * 16 + g * 4 + rr;
                f16x4 o = {(_Float16)dj[0], (_Float16)dj[1], (_Float16)dj[2], (_Float16)dj[3]};
                *(f16x4*)&pmin[(size_t)row * NGROUP + gb] = o;
            }
        }
    }
}

// ---------------- VQ scan: wave-per-row, 16-code groups, fp16 pmin ----------------
__global__ __launch_bounds__(256)
void vq_scan(const _Float16* __restrict__ pmin, const float* __restrict__ ze32,
             const float* __restrict__ E32, const float* __restrict__ e2s,
             const float* __restrict__ z2,
             float* __restrict__ nn_out, float* __restrict__ zq_out,
             float* __restrict__ ze_next, float* __restrict__ z2_next,
             unsigned short* __restrict__ zebf_next) {
    __shared__ float zer[4][CD];
    __shared__ int glist[4][NGROUP];
    int w = threadIdx.x >> 6, lane = threadIdx.x & 63;
    int row = blockIdx.x * 4 + w;

    // 1. stage this wave's row into LDS (and keep own chunk in regs for epilogue)
    float4 zv = *(const float4*)(ze32 + (size_t)row * CD + lane * 4);
    *(float4*)&zer[w][lane * 4] = zv;

    // 2. group-min scan: 256 groups across 64 lanes (4 each), shuffle min-reduce
    const _Float16* pm = pmin + (size_t)row * NGROUP;
    float p0 = (float)pm[lane];
    float p1 = (float)pm[64 + lane];
    float p2 = (float)pm[128 + lane];
    float p3 = (float)pm[192 + lane];
    float m = fminf(fminf(p0, p1), fminf(p2, p3));
#pragma unroll
    for (int off = 32; off > 0; off >>= 1) m = fminf(m, __shfl_xor(m, off, 64));
    float lim = m + MARGIN;

    // 3. candidate list via ballot prefix (order deterministic, no atomics)
    bool f0 = p0 <= lim, f1 = p1 <= lim, f2 = p2 <= lim, f3 = p3 <= lim;
    unsigned long long b0 = __ballot(f0), b1 = __ballot(f1);
    unsigned long long b2 = __ballot(f2), b3 = __ballot(f3);
    unsigned long long lm = (1ull << lane) - 1ull;
    int c0 = __popcll(b0), c1 = __popcll(b1), c2 = __popcll(b2), c3 = __popcll(b3);
    int base1 = c0, base2 = c0 + c1, base3 = c0 + c1 + c2;
    int cnt = base3 + c3;
    if (f0) glist[w][__popcll(b0 & lm)] = lane;
    if (f1) glist[w][base1 + __popcll(b1 & lm)] = 64 + lane;
    if (f2) glist[w][base2 + __popcll(b2 & lm)] = 128 + lane;
    if (f3) glist[w][base3 + __popcll(b3 & lm)] = 192 + lane;
    // in-wave LDS visibility: drain our ds_writes before reading
    asm volatile("s_waitcnt lgkmcnt(0)" ::: "memory");

    // 4. fp32 rescore of candidates (same accumulation order as before)
    float z2row = z2[row];
    int ncand = cnt * 16;
    unsigned long long localbest = ~0ull;
    for (int ci = lane; ci < ncand; ci += 64) {
        int n = glist[w][ci >> 4] * 16 + (ci & 15);
        float e2n = e2s[n];
        const float* er = E32 + (size_t)n * CD;
        float s = 0.f;
#pragma unroll 8
        for (int k = 0; k < CD; k += 4) {
            float4 eb = *(const float4*)(er + k);
            s = fmaf(zer[w][k + 0], eb.x, s);
            s = fmaf(zer[w][k + 1], eb.y, s);
            s = fmaf(zer[w][k + 2], eb.z, s);
            s = fmaf(zer[w][k + 3], eb.w, s);
        }
        float d32 = (z2row - 2.0f * s) + e2n;
        unsigned long long key =
            ((unsigned long long)__float_as_uint(d32) << 32) | (unsigned)n;
        localbest = (key < localbest) ? key : localbest;
    }
    // 5. wave argmin of packed key (tie-break = lowest n, order-independent)
#pragma unroll
    for (int off = 32; off > 0; off >>= 1) {
        unsigned long long o = __shfl_xor(localbest, off, 64);
        localbest = (o < localbest) ? o : localbest;
    }
    int idx = (int)(unsigned)(localbest & 0xFFFFFFFFull);
    if (lane == 0) nn_out[row] = (float)idx;

    // 6. gather + residual (identical arithmetic/order to prior version)
    float4 e = *(const float4*)(E32 + (size_t)idx * CD + lane * 4);
    float4 z = zv;
    *(float4*)(zq_out + (size_t)row * CD + lane * 4) = e;
    if (ze_next) {
        float4 r = make_float4(z.x - e.x, z.y - e.y, z.z - e.z, z.w - e.w);
        *(float4*)(ze_next + (size_t)row * CD + lane * 4) = r;
        ushort4 o = make_ushort4(f2bf(r.x), f2bf(r.y), f2bf(r.z), f2bf(r.w));
        *(ushort4*)(zebf_next + (size_t)row * CD + lane * 4) = o;
        float s = r.x * r.x + r.y * r.y + r.z * r.z + r.w * r.w;
        s = wave_sum(s);
        if (lane == 0) z2_next[row] = s;
    }
}

// ---------------- decoder input compose -> bf16 ----------------
__global__ void dcvt_kernel(const float* __restrict__ ze1, const float* __restrict__ q1,
                            const float* __restrict__ q2, const float* __restrict__ q3,
                            const float* __restrict__ q4, unsigned short* __restrict__ dibf) {
    size_t off = (size_t)(blockIdx.x * blockDim.x + threadIdx.x) * 4;
    float4 z = *(const float4*)(ze1 + off);
    float4 a = *(const float4*)(q1 + off);
    float4 b = *(const float4*)(q2 + off);
    float4 c = *(const float4*)(q3 + off);
    float4 d = *(const float4*)(q4 + off);
    float sx = ((a.x + b.x) + c.x) + d.x;
    float sy = ((a.y + b.y) + c.y) + d.y;
    float sz = ((a.z + b.z) + c.z) + d.z;
    float sw = ((a.w + b.w) + c.w) + d.w;
    ushort4 o = make_ushort4(f2bf(z.x + (sx - z.x)), f2bf(z.y + (sy - z.y)),
                             f2bf(z.z + (sz - z.z)), f2bf(z.w + (sw - z.w)));
    *(ushort4*)(dibf + off) = o;
}

// ---------------- decoder MFMA: xhat = dibf @ WdT^T + b_dec ----------------
__global__ __launch_bounds__(256)
void dec_mfma(const unsigned short* __restrict__ dibf, const unsigned short* __restrict__ WdT,
              const float* __restrict__ bias, float* __restrict__ C) {
    __shared__ unsigned short As[BM * BK];
    __shared__ unsigned short Bs[BN * BK];
    int mb = blockIdx.x / 6, nb = blockIdx.x % 6;
    int mBase = mb * BM, nBase = nb * BN;
    int t = threadIdx.x;
    f32x4 acc[4][4];
    f32x4 zero = {0.f, 0.f, 0.f, 0.f};
#pragma unroll
    for (int i = 0; i < 4; ++i)
#pragma unroll
        for (int j = 0; j < 4; ++j) acc[i][j] = zero;

    mfma_core(dibf, WdT, mBase, nBase, As, Bs, acc, t);

    int w = t >> 6, lane = t & 63;
    int wm = (w >> 1) * 64, wn = (w & 1) * 64;
    int g = lane >> 4, c = lane & 15;
    float bv[4];
#pragma unroll
    for (int j = 0; j < 4; ++j) bv[j] = bias[nBase + wn + j * 16 + c];
#pragma unroll
    for (int i = 0; i < 4; ++i)
#pragma unroll
        for (int rr = 0; rr < 4; ++rr) {
            int row = mBase + wm + i * 16 + g * 4 + rr;
#pragma unroll
            for (int j = 0; j < 4; ++j)
                C[(size_t)row * DIMIN + nBase + wn + j * 16 + c] = acc[i][j][rr] + bv[j];
        }
}

// ---------------- launch ----------------
extern "C" void kernel_launch(void* const* d_in, const int* in_sizes, int n_in,
                              void* d_out, int out_size, void* d_ws, size_t ws_size,
                              hipStream_t stream) {
    const float* x     = (const float*)d_in[0];
    const float* W_enc = (const float*)d_in[1];
    const float* b_enc = (const float*)d_in[2];
    const float* Ecb[4] = {(const float*)d_in[3], (const float*)d_in[4],
                           (const float*)d_in[5], (const float*)d_in[6]};
    const float* W_dec = (const float*)d_in[7];
    const float* b_dec = (const float*)d_in[8];

    float* out  = (float*)d_out;
    float* xhat = out;
    float* ze[4];
    float* zq[4];
    float* nn[4];
    size_t off = (size_t)NROWS * DIMIN;
    for (int i = 0; i < 4; ++i) { ze[i] = out + off; off += (size_t)NROWS * CD; }
    for (int i = 0; i < 4; ++i) { zq[i] = out + off; off += (size_t)NROWS * CD; }
    for (int i = 0; i < 4; ++i) { nn[i] = out + off; off += NROWS; }

    unsigned char* wsb = (unsigned char*)d_ws;
    float* z2            = (float*)wsb;                              // 64 KB
    float* e2            = (float*)(wsb + 65536);                    // 64 KB
    unsigned short* WdT  = (unsigned short*)(wsb + 131072);          // 384 KB
    _Float16* pmin       = (_Float16*)(wsb + 524288);                // 8 MB (16384 x 256 fp16)
    unsigned short* dibf = (unsigned short*)(wsb + 524288);          // aliases pmin (dead after VQ loop)
    unsigned short* Ebf  = (unsigned short*)(wsb + 8912896);         // 8 MB
    unsigned short* zebf = (unsigned short*)(wsb + 17301504);        // 8 MB

    // fused: enc GEMM (1024 blocks) || ecvt (4096) || wcvt (768)
    preamble_kernel<<<5888, 256, 0, stream>>>(x, W_enc, b_enc, ze[0],
                                              Ecb[0], Ecb[1], Ecb[2], Ecb[3], Ebf, e2,
                                              W_dec, WdT);
    zecvt_kernel<<<4096, 256, 0, stream>>>(ze[0], zebf, z2);

    for (int s = 0; s < 4; ++s) {
        vq_minA<<<4096, 256, 0, stream>>>(zebf, Ebf + (size_t)s * KC * CD,
                                          e2 + (size_t)s * KC, pmin);
        vq_scan<<<NROWS / 4, 256, 0, stream>>>(pmin, ze[s], Ecb[s], e2 + (size_t)s * KC, z2,
                                               nn[s], zq[s],
                                               (s < 3) ? ze[s + 1] : nullptr, z2, zebf);
    }
    dcvt_kernel<<<4096, 256, 0, stream>>>(ze[0], zq[0], zq[1], zq[2], zq[3], dibf);
    dec_mfma<<<768, 256, 0, stream>>>(dibf, WdT, b_dec, xhat);
}

// Round 8
// 859.834 us; speedup vs baseline: 1.0598x; 1.0598x over previous
//
#include <hip/hip_runtime.h>

#define NROWS 16384
#define DIMIN 768
#define CD    256
#define KC    4096

#define BM 128
#define BN 128
#define BK 32
#define MARGIN 0.035f
#define NGROUP 256   // 4096 codes / 16 per group

typedef __attribute__((ext_vector_type(8))) short short8;
typedef __attribute__((ext_vector_type(4))) float f32x4;
typedef __attribute__((ext_vector_type(2))) _Float16 f16x2;

#define SWZ(r) ((((r) + ((r) >> 2))) & 3)
#define ASYNC_CP16(gp, lp)                                                     \
    __builtin_amdgcn_global_load_lds(                                          \
        (const __attribute__((address_space(1))) void*)(gp),                   \
        (__attribute__((address_space(3))) void*)(lp), 16, 0, 0)

// ---------------- helpers ----------------
__device__ __forceinline__ float wave_sum(float v) {
#pragma unroll
    for (int off = 32; off > 0; off >>= 1) v += __shfl_xor(v, off, 64);
    return v;
}
__device__ __forceinline__ unsigned short f2bf(float f) {
    unsigned u = __float_as_uint(f);
    unsigned r = (u + 0x7FFFu + ((u >> 16) & 1u)) >> 16;
    return (unsigned short)r;
}

// ---------------- shared MFMA core: acc[i][j] += Arows_tile . Brows_tile^T ----------------
__device__ __forceinline__ void mfma_core(const unsigned short* __restrict__ Arows,
                                          const unsigned short* __restrict__ Brows,
                                          int mBase, int nBase,
                                          unsigned short* As, unsigned short* Bs,
                                          f32x4 acc[4][4], int t) {
    int w = t >> 6, lane = t & 63;
    int wm = (w >> 1) * 64, wn = (w & 1) * 64;
    int g = lane >> 4, c = lane & 15;

    for (int kB = 0; kB < CD; kB += BK) {
        __syncthreads();
#pragma unroll
        for (int it = 0; it < 2; ++it) {
            int L = w * 128 + it * 64 + lane;  // 16B-chunk index in tile
            int r = L >> 2, p = L & 3;
            int q = p ^ SWZ(r);
            ASYNC_CP16(Arows + (size_t)(mBase + r) * CD + kB + q * 8,
                       &As[(w * 128 + it * 64) * 8]);
            ASYNC_CP16(Brows + (size_t)(nBase + r) * CD + kB + q * 8,
                       &Bs[(w * 128 + it * 64) * 8]);
        }
        __syncthreads();
        short8 a[4], b[4];
#pragma unroll
        for (int i = 0; i < 4; ++i) {
            int ra = wm + i * 16 + c;
            a[i] = *(const short8*)&As[ra * 32 + ((g ^ SWZ(ra)) << 3)];
            int rb = wn + i * 16 + c;
            b[i] = *(const short8*)&Bs[rb * 32 + ((g ^ SWZ(rb)) << 3)];
        }
#pragma unroll
        for (int i = 0; i < 4; ++i)
#pragma unroll
            for (int j = 0; j < 4; ++j)
                acc[i][j] = __builtin_amdgcn_mfma_f32_16x16x32_bf16(a[i], b[j], acc[i][j], 0, 0, 0);
    }
}

// ---------------- fused preamble: enc GEMM (blocks 0..1023) ||
//                  E->bf16+e2 (blocks 1024..5119) || W_dec->WdT (blocks 5120..5887) ----------------
__global__ __launch_bounds__(256)
void preamble_kernel(const float* __restrict__ A, const float* __restrict__ B,
                     const float* __restrict__ bias, float* __restrict__ C,
                     const float* __restrict__ E1, const float* __restrict__ E2,
                     const float* __restrict__ E3, const float* __restrict__ E4,
                     unsigned short* __restrict__ Ebf, float* __restrict__ e2,
                     const float* __restrict__ Wd, unsigned short* __restrict__ WdT) {
    int bid = blockIdx.x;
    int t = threadIdx.x;
    if (bid < 1024) {
        // ---- fp32 encoder GEMM, 64x64 tiles (identical to enc_gemm64) ----
        __shared__ float As[BK][64 + 4];
        __shared__ float Bs[BK][64 + 4];
        const int Kt = DIMIN, Nt = CD;
        int mb = bid >> 2, nb = bid & 3;
        int mBase = mb * 64, nBase = nb * 64;
        int mg = t >> 4, ng = t & 15;

        float acc[4][4];
#pragma unroll
        for (int i = 0; i < 4; ++i)
#pragma unroll
            for (int j = 0; j < 4; ++j) acc[i][j] = 0.f;

        for (int kB = 0; kB < Kt; kB += BK) {
#pragma unroll
            for (int i = 0; i < 2; ++i) {  // stage A (transpose)
                int idx = i * 256 + t;
                int row = idx >> 3, k4 = idx & 7;
                float4 g = *(const float4*)(A + (size_t)(mBase + row) * Kt + kB + k4 * 4);
                As[k4 * 4 + 0][row] = g.x;
                As[k4 * 4 + 1][row] = g.y;
                As[k4 * 4 + 2][row] = g.z;
                As[k4 * 4 + 3][row] = g.w;
            }
#pragma unroll
            for (int i = 0; i < 2; ++i) {  // stage B
                int idx = i * 256 + t;
                int row = idx >> 4, c4 = idx & 15;
                float4 g = *(const float4*)(B + (size_t)(kB + row) * Nt + nBase + c4 * 4);
                *(float4*)&Bs[row][c4 * 4] = g;
            }
            __syncthreads();
#pragma unroll 8
            for (int kk = 0; kk < BK; ++kk) {
                float4 a0 = *(const float4*)&As[kk][mg * 4];
                float4 b0 = *(const float4*)&Bs[kk][ng * 4];
                float av[4] = {a0.x, a0.y, a0.z, a0.w};
                float bv[4] = {b0.x, b0.y, b0.z, b0.w};
#pragma unroll
                for (int im = 0; im < 4; ++im)
#pragma unroll
                    for (int in = 0; in < 4; ++in)
                        acc[im][in] = fmaf(av[im], bv[in], acc[im][in]);
            }
            __syncthreads();
        }
        float bv[4];
#pragma unroll
        for (int in = 0; in < 4; ++in) bv[in] = bias[nBase + ng * 4 + in];
#pragma unroll
        for (int im = 0; im < 4; ++im) {
            float4 o = make_float4(acc[im][0] + bv[0], acc[im][1] + bv[1],
                                   acc[im][2] + bv[2], acc[im][3] + bv[3]);
            *(float4*)(C + (size_t)(mBase + mg * 4 + im) * Nt + nBase + ng * 4) = o;
        }
    } else if (bid < 1024 + 4096) {
        // ---- E -> bf16 + e2 (identical to ecvt_kernel) ----
        int vb = bid - 1024;
        int gw   = (vb * 256 + t) >> 6;  // 0..16383
        int lane = t & 63;
        int cb = gw >> 12, r = gw & (KC - 1);
        const float* E = (cb == 0) ? E1 : (cb == 1) ? E2 : (cb == 2) ? E3 : E4;
        float4 v = *(const float4*)(E + (size_t)r * CD + lane * 4);
        float s  = v.x * v.x + v.y * v.y + v.z * v.z + v.w * v.w;
        s = wave_sum(s);
        if (lane == 0) e2[gw] = s;
        ushort4 o = make_ushort4(f2bf(v.x), f2bf(v.y), f2bf(v.z), f2bf(v.w));
        *(ushort4*)(Ebf + (size_t)gw * CD + lane * 4) = o;
    } else {
        // ---- W_dec (256x768) -> WdT (768x256 bf16, transposed) ----
        int vb = bid - (1024 + 4096);
        int gid = vb * 256 + t;  // 0..196607
        int k = gid / DIMIN, n = gid % DIMIN;
        WdT[(size_t)n * CD + k] = f2bf(Wd[gid]);
    }
}

// ---------------- ze1 -> bf16 + z2 ----------------
__global__ void zecvt_kernel(const float* __restrict__ ze, unsigned short* __restrict__ zebf,
                             float* __restrict__ z2) {
    int gw   = (blockIdx.x * blockDim.x + threadIdx.x) >> 6;
    int lane = threadIdx.x & 63;
    float4 v = *(const float4*)(ze + (size_t)gw * CD + lane * 4);
    float s  = v.x * v.x + v.y * v.y + v.z * v.z + v.w * v.w;
    s = wave_sum(s);
    if (lane == 0) z2[gw] = s;
    ushort4 o = make_ushort4(f2bf(v.x), f2bf(v.y), f2bf(v.z), f2bf(v.w));
    *(ushort4*)(zebf + (size_t)gw * CD + lane * 4) = o;
}

// ---------------- VQ pass A: d' = e2 - 2*(ze.E^T) bf16 MFMA, per-16-code-group min (fp16) ----------------
// Epilogue converts dj to fp16 BEFORE the cross-lane min (RNE fp32->fp16 is monotone, so
// min of converted == converted min, bit-identical) and reduces 2 packed halves ->
// 8 shuffles + 8 packed mins instead of 16 + 16.
__global__ __launch_bounds__(256)
void vq_minA(const unsigned short* __restrict__ zebf, const unsigned short* __restrict__ Ebf,
             const float* __restrict__ e2s, _Float16* __restrict__ pmin) {
    __shared__ unsigned short As[BM * BK];
    __shared__ unsigned short Bs[BN * BK];
    int mBase = (blockIdx.x >> 5) * BM;
    int nBase = (blockIdx.x & 31) * BN;
    int t = threadIdx.x;
    f32x4 acc[4][4];
    f32x4 zero = {0.f, 0.f, 0.f, 0.f};
#pragma unroll
    for (int i = 0; i < 4; ++i)
#pragma unroll
        for (int j = 0; j < 4; ++j) acc[i][j] = zero;

    mfma_core(zebf, Ebf, mBase, nBase, As, Bs, acc, t);

    int w = t >> 6, lane = t & 63;
    int wm = (w >> 1) * 64, wn = (w & 1) * 64;
    int g = lane >> 4, c = lane & 15;
    float e2v[4];
#pragma unroll
    for (int j = 0; j < 4; ++j) e2v[j] = e2s[nBase + wn + j * 16 + c];
    int gb = (nBase + wn) >> 4;  // first of 4 consecutive 16-code groups this lane covers
#pragma unroll
    for (int i = 0; i < 4; ++i) {
#pragma unroll
        for (int rr = 0; rr < 4; ++rr) {
            float dj[4];
#pragma unroll
            for (int j = 0; j < 4; ++j) dj[j] = fmaf(-2.f, acc[i][j][rr], e2v[j]);
            // convert to fp16 (RNE), pack pairs, then min over the 16 c-lanes
            f16x2 ha, hb;
            ha[0] = (_Float16)dj[0]; ha[1] = (_Float16)dj[1];
            hb[0] = (_Float16)dj[2]; hb[1] = (_Float16)dj[3];
            unsigned ua = __builtin_bit_cast(unsigned, ha);
            unsigned ub = __builtin_bit_cast(unsigned, hb);
#pragma unroll
            for (int off = 1; off < 16; off <<= 1) {
                unsigned sa = __shfl_xor(ua, off, 64);
                unsigned sb = __shfl_xor(ub, off, 64);
                f16x2 va = __builtin_elementwise_min(__builtin_bit_cast(f16x2, ua),
                                                     __builtin_bit_cast(f16x2, sa));
                f16x2 vb = __builtin_elementwise_min(__builtin_bit_cast(f16x2, ub),
                                                     __builtin_bit_cast(f16x2, sb));
                ua = __builtin_bit_cast(unsigned, va);
                ub = __builtin_bit_cast(unsigned, vb);
            }
            if (c == 0) {
                int row = mBase + wm + i * 16 + g * 4 + rr;
                uint2 o;
                o.x = ua;
                o.y = ub;
                *(uint2*)&pmin[(size_t)row * NGROUP + gb] = o;  // gb % 4 == 0 -> 8B aligned
            }
        }
    }
}

// ---------------- VQ scan: wave-per-row, 16-code groups, fp16 pmin ----------------
__global__ __launch_bounds__(256)
void vq_scan(const _Float16* __restrict__ pmin, const float* __restrict__ ze32,
             const float* __restrict__ E32, const float* __restrict__ e2s,
             const float* __restrict__ z2,
             float* __restrict__ nn_out, float* __restrict__ zq_out,
             float* __restrict__ ze_next, float* __restrict__ z2_next,
             unsigned short* __restrict__ zebf_next) {
    __shared__ float zer[4][CD];
    __shared__ int glist[4][NGROUP];
    int w = threadIdx.x >> 6, lane = threadIdx.x & 63;
    int row = blockIdx.x * 4 + w;

    // 1. stage this wave's row into LDS (and keep own chunk in regs for epilogue)
    float4 zv = *(const float4*)(ze32 + (size_t)row * CD + lane * 4);
    *(float4*)&zer[w][lane * 4] = zv;

    // 2. group-min scan: 256 groups across 64 lanes (4 each), shuffle min-reduce
    const _Float16* pm = pmin + (size_t)row * NGROUP;
    float p0 = (float)pm[lane];
    float p1 = (float)pm[64 + lane];
    float p2 = (float)pm[128 + lane];
    float p3 = (float)pm[192 + lane];
    float m = fminf(fminf(p0, p1), fminf(p2, p3));
#pragma unroll
    for (int off = 32; off > 0; off >>= 1) m = fminf(m, __shfl_xor(m, off, 64));
    float lim = m + MARGIN;

    // 3. candidate list via ballot prefix (order deterministic, no atomics)
    bool f0 = p0 <= lim, f1 = p1 <= lim, f2 = p2 <= lim, f3 = p3 <= lim;
    unsigned long long b0 = __ballot(f0), b1 = __ballot(f1);
    unsigned long long b2 = __ballot(f2), b3 = __ballot(f3);
    unsigned long long lm = (1ull << lane) - 1ull;
    int c0 = __popcll(b0), c1 = __popcll(b1), c2 = __popcll(b2), c3 = __popcll(b3);
    int base1 = c0, base2 = c0 + c1, base3 = c0 + c1 + c2;
    int cnt = base3 + c3;
    if (f0) glist[w][__popcll(b0 & lm)] = lane;
    if (f1) glist[w][base1 + __popcll(b1 & lm)] = 64 + lane;
    if (f2) glist[w][base2 + __popcll(b2 & lm)] = 128 + lane;
    if (f3) glist[w][base3 + __popcll(b3 & lm)] = 192 + lane;
    // in-wave LDS visibility: drain our ds_writes before reading
    asm volatile("s_waitcnt lgkmcnt(0)" ::: "memory");

    // 4. fp32 rescore of candidates (same accumulation order as before)
    float z2row = z2[row];
    int ncand = cnt * 16;
    unsigned long long localbest = ~0ull;
    for (int ci = lane; ci < ncand; ci += 64) {
        int n = glist[w][ci >> 4] * 16 + (ci & 15);
        float e2n = e2s[n];
        const float* er = E32 + (size_t)n * CD;
        float s = 0.f;
#pragma unroll 8
        for (int k = 0; k < CD; k += 4) {
            float4 eb = *(const float4*)(er + k);
            s = fmaf(zer[w][k + 0], eb.x, s);
            s = fmaf(zer[w][k + 1], eb.y, s);
            s = fmaf(zer[w][k + 2], eb.z, s);
            s = fmaf(zer[w][k + 3], eb.w, s);
        }
        float d32 = (z2row - 2.0f * s) + e2n;
        unsigned long long key =
            ((unsigned long long)__float_as_uint(d32) << 32) | (unsigned)n;
        localbest = (key < localbest) ? key : localbest;
    }
    // 5. wave argmin of packed key (tie-break = lowest n, order-independent)
#pragma unroll
    for (int off = 32; off > 0; off >>= 1) {
        unsigned long long o = __shfl_xor(localbest, off, 64);
        localbest = (o < localbest) ? o : localbest;
    }
    int idx = (int)(unsigned)(localbest & 0xFFFFFFFFull);
    if (lane == 0) nn_out[row] = (float)idx;

    // 6. gather + residual (identical arithmetic/order to prior version)
    float4 e = *(const float4*)(E32 + (size_t)idx * CD + lane * 4);
    float4 z = zv;
    *(float4*)(zq_out + (size_t)row * CD + lane * 4) = e;
    if (ze_next) {
        float4 r = make_float4(z.x - e.x, z.y - e.y, z.z - e.z, z.w - e.w);
        *(float4*)(ze_next + (size_t)row * CD + lane * 4) = r;
        ushort4 o = make_ushort4(f2bf(r.x), f2bf(r.y), f2bf(r.z), f2bf(r.w));
        *(ushort4*)(zebf_next + (size_t)row * CD + lane * 4) = o;
        float s = r.x * r.x + r.y * r.y + r.z * r.z + r.w * r.w;
        s = wave_sum(s);
        if (lane == 0) z2_next[row] = s;
    }
}

// ---------------- decoder input compose -> bf16 ----------------
__global__ void dcvt_kernel(const float* __restrict__ ze1, const float* __restrict__ q1,
                            const float* __restrict__ q2, const float* __restrict__ q3,
                            const float* __restrict__ q4, unsigned short* __restrict__ dibf) {
    size_t off = (size_t)(blockIdx.x * blockDim.x + threadIdx.x) * 4;
    float4 z = *(const float4*)(ze1 + off);
    float4 a = *(const float4*)(q1 + off);
    float4 b = *(const float4*)(q2 + off);
    float4 c = *(const float4*)(q3 + off);
    float4 d = *(const float4*)(q4 + off);
    float sx = ((a.x + b.x) + c.x) + d.x;
    float sy = ((a.y + b.y) + c.y) + d.y;
    float sz = ((a.z + b.z) + c.z) + d.z;
    float sw = ((a.w + b.w) + c.w) + d.w;
    ushort4 o = make_ushort4(f2bf(z.x + (sx - z.x)), f2bf(z.y + (sy - z.y)),
                             f2bf(z.z + (sz - z.z)), f2bf(z.w + (sw - z.w)));
    *(ushort4*)(dibf + off) = o;
}

// ---------------- decoder MFMA: xhat = dibf @ WdT^T + b_dec ----------------
__global__ __launch_bounds__(256)
void dec_mfma(const unsigned short* __restrict__ dibf, const unsigned short* __restrict__ WdT,
              const float* __restrict__ bias, float* __restrict__ C) {
    __shared__ unsigned short As[BM * BK];
    __shared__ unsigned short Bs[BN * BK];
    int mb = blockIdx.x / 6, nb = blockIdx.x % 6;
    int mBase = mb * BM, nBase = nb * BN;
    int t = threadIdx.x;
    f32x4 acc[4][4];
    f32x4 zero = {0.f, 0.f, 0.f, 0.f};
#pragma unroll
    for (int i = 0; i < 4; ++i)
#pragma unroll
        for (int j = 0; j < 4; ++j) acc[i][j] = zero;

    mfma_core(dibf, WdT, mBase, nBase, As, Bs, acc, t);

    int w = t >> 6, lane = t & 63;
    int wm = (w >> 1) * 64, wn = (w & 1) * 64;
    int g = lane >> 4, c = lane & 15;
    float bv[4];
#pragma unroll
    for (int j = 0; j < 4; ++j) bv[j] = bias[nBase + wn + j * 16 + c];
#pragma unroll
    for (int i = 0; i < 4; ++i)
#pragma unroll
        for (int rr = 0; rr < 4; ++rr) {
            int row = mBase + wm + i * 16 + g * 4 + rr;
#pragma unroll
            for (int j = 0; j < 4; ++j)
                C[(size_t)row * DIMIN + nBase + wn + j * 16 + c] = acc[i][j][rr] + bv[j];
        }
}

// ---------------- launch ----------------
extern "C" void kernel_launch(void* const* d_in, const int* in_sizes, int n_in,
                              void* d_out, int out_size, void* d_ws, size_t ws_size,
                              hipStream_t stream) {
    const float* x     = (const float*)d_in[0];
    const float* W_enc = (const float*)d_in[1];
    const float* b_enc = (const float*)d_in[2];
    const float* Ecb[4] = {(const float*)d_in[3], (const float*)d_in[4],
                           (const float*)d_in[5], (const float*)d_in[6]};
    const float* W_dec = (const float*)d_in[7];
    const float* b_dec = (const float*)d_in[8];

    float* out  = (float*)d_out;
    float* xhat = out;
    float* ze[4];
    float* zq[4];
    float* nn[4];
    size_t off = (size_t)NROWS * DIMIN;
    for (int i = 0; i < 4; ++i) { ze[i] = out + off; off += (size_t)NROWS * CD; }
    for (int i = 0; i < 4; ++i) { zq[i] = out + off; off += (size_t)NROWS * CD; }
    for (int i = 0; i < 4; ++i) { nn[i] = out + off; off += NROWS; }

    unsigned char* wsb = (unsigned char*)d_ws;
    float* z2            = (float*)wsb;                              // 64 KB
    float* e2            = (float*)(wsb + 65536);                    // 64 KB
    unsigned short* WdT  = (unsigned short*)(wsb + 131072);          // 384 KB
    _Float16* pmin       = (_Float16*)(wsb + 524288);                // 8 MB (16384 x 256 fp16)
    unsigned short* dibf = (unsigned short*)(wsb + 524288);          // aliases pmin (dead after VQ loop)
    unsigned short* Ebf  = (unsigned short*)(wsb + 8912896);         // 8 MB
    unsigned short* zebf = (unsigned short*)(wsb + 17301504);        // 8 MB

    // fused: enc GEMM (1024 blocks) || ecvt (4096) || wcvt (768)
    preamble_kernel<<<5888, 256, 0, stream>>>(x, W_enc, b_enc, ze[0],
                                              Ecb[0], Ecb[1], Ecb[2], Ecb[3], Ebf, e2,
                                              W_dec, WdT);
    zecvt_kernel<<<4096, 256, 0, stream>>>(ze[0], zebf, z2);

    for (int s = 0; s < 4; ++s) {
        vq_minA<<<4096, 256, 0, stream>>>(zebf, Ebf + (size_t)s * KC * CD,
                                          e2 + (size_t)s * KC, pmin);
        vq_scan<<<NROWS / 4, 256, 0, stream>>>(pmin, ze[s], Ecb[s], e2 + (size_t)s * KC, z2,
                                               nn[s], zq[s],
                                               (s < 3) ? ze[s + 1] : nullptr, z2, zebf);
    }
    dcvt_kernel<<<4096, 256, 0, stream>>>(ze[0], zq[0], zq[1], zq[2], zq[3], dibf);
    dec_mfma<<<768, 256, 0, stream>>>(dibf, WdT, b_dec, xhat);
}